// Round 4
// baseline (543.496 us; speedup 1.0000x reference)
//
#include <hip/hip_runtime.h>
#include <math.h>

// x fp32 [B=8, C=64, S=32*128*128=524288]
// norm over C, avg+max over S, relu, sigmoid(out^2) -> [B,C]
#define NC   64
#define NS   524288
#define NB   8
#define BPB  256               // blocks per batch
#define CHUNK 8                // chunks per block
#define P    256               // positions per chunk (64 lanes x float4)

// Register-resident + 2-deep ping-pong prefetch, POINTER-FREE (rule #20):
// chunk bodies are macro-instantiated with array NAMES so va/vb never have
// their address taken -> SROA keeps them in VGPRs (round-3 failure mode was
// the `float4* v = cond ? vb : va` scratch demotion).
__global__ __launch_bounds__(256, 2)
void ca_partial(const float* __restrict__ x, float* __restrict__ ws) {
    __shared__ float nsq_s[2][4][P];

    const int b   = blockIdx.y;
    const int blk = blockIdx.x;
    const int t   = threadIdx.x;
    const int w   = t >> 6;     // wave id 0..3
    const int k   = t & 63;     // lane

    float run_sum[16], run_max[16];
    #pragma unroll
    for (int i = 0; i < 16; ++i) { run_sum[i] = 0.0f; run_max[i] = -INFINITY; }

    const float* xb = x + (size_t)b * NC * NS + (size_t)w * NS + 4 * k;

    float4 va[16], vb[16];

    // prologue: load chunk 0 into va
    {
        const float* pb = xb + (size_t)(blk * CHUNK) * P;
        #pragma unroll
        for (int i = 0; i < 16; ++i)
            va[i] = *reinterpret_cast<const float4*>(pb + (size_t)(4 * i) * NS);
    }

// One chunk: prefetch next into U (stays in flight across the raw barrier),
// reduce norm^2 of V, exchange via parity LDS buffer, normalize+accumulate V.
#define STEP(V, U, CH, PREFETCH)                                              \
    {                                                                         \
        if (PREFETCH) {                                                       \
            const float* pb = xb + (size_t)((blk * CHUNK + (CH) + 1)) * P;    \
            _Pragma("unroll")                                                 \
            for (int i = 0; i < 16; ++i)                                      \
                U[i] = *reinterpret_cast<const float4*>(pb + (size_t)(4 * i) * NS); \
        }                                                                     \
        float nx = 0.f, ny = 0.f, nz = 0.f, nw2 = 0.f;                        \
        _Pragma("unroll")                                                     \
        for (int i = 0; i < 16; ++i) {                                        \
            nx  = fmaf(V[i].x, V[i].x, nx);                                   \
            ny  = fmaf(V[i].y, V[i].y, ny);                                   \
            nz  = fmaf(V[i].z, V[i].z, nz);                                   \
            nw2 = fmaf(V[i].w, V[i].w, nw2);                                  \
        }                                                                     \
        *reinterpret_cast<float4*>(&nsq_s[(CH) & 1][w][4 * k]) =              \
            make_float4(nx, ny, nz, nw2);                                     \
        asm volatile("s_waitcnt lgkmcnt(0)" ::: "memory");                    \
        __builtin_amdgcn_s_barrier();                                         \
        asm volatile("" ::: "memory");                                        \
        const float4 q0 = *reinterpret_cast<const float4*>(&nsq_s[(CH) & 1][0][4 * k]); \
        const float4 q1 = *reinterpret_cast<const float4*>(&nsq_s[(CH) & 1][1][4 * k]); \
        const float4 q2 = *reinterpret_cast<const float4*>(&nsq_s[(CH) & 1][2][4 * k]); \
        const float4 q3 = *reinterpret_cast<const float4*>(&nsq_s[(CH) & 1][3][4 * k]); \
        const float rx = 1.0f / fmaxf(sqrtf(q0.x + q1.x + q2.x + q3.x), 1e-12f); \
        const float ry = 1.0f / fmaxf(sqrtf(q0.y + q1.y + q2.y + q3.y), 1e-12f); \
        const float rz = 1.0f / fmaxf(sqrtf(q0.z + q1.z + q2.z + q3.z), 1e-12f); \
        const float rw = 1.0f / fmaxf(sqrtf(q0.w + q1.w + q2.w + q3.w), 1e-12f); \
        _Pragma("unroll")                                                     \
        for (int i = 0; i < 16; ++i) {                                        \
            run_sum[i] = fmaf(V[i].x, rx, run_sum[i]);                        \
            run_sum[i] = fmaf(V[i].y, ry, run_sum[i]);                        \
            run_sum[i] = fmaf(V[i].z, rz, run_sum[i]);                        \
            run_sum[i] = fmaf(V[i].w, rw, run_sum[i]);                        \
            const float m0 = fmaxf(V[i].x * rx, V[i].y * ry);                 \
            const float m1 = fmaxf(V[i].z * rz, V[i].w * rw);                 \
            run_max[i] = fmaxf(run_max[i], fmaxf(m0, m1));                    \
        }                                                                     \
    }

    STEP(va, vb, 0, 1)
    STEP(vb, va, 1, 1)
    STEP(va, vb, 2, 1)
    STEP(vb, va, 3, 1)
    STEP(va, vb, 4, 1)
    STEP(vb, va, 5, 1)
    STEP(va, vb, 6, 1)
    STEP(vb, va, 7, 0)
#undef STEP

    // ---- one-time wave butterfly reduce, lane 0 writes partials ----
    float* wp = ws + (size_t)(b * BPB + blk) * (2 * NC);
    #pragma unroll
    for (int i = 0; i < 16; ++i) {
        float s = run_sum[i];
        float m = run_max[i];
        #pragma unroll
        for (int d = 32; d > 0; d >>= 1) {
            s += __shfl_xor(s, d, 64);
            m = fmaxf(m, __shfl_xor(m, d, 64));
        }
        if (k == 0) {
            wp[4 * i + w]      = s;   // channel c = 4i+w
            wp[NC + 4 * i + w] = m;
        }
    }
}

// Reduce BPB partials per (b,c), apply relu + sigmoid(out^2).
__global__ __launch_bounds__(1024)
void ca_final(const float* __restrict__ ws, float* __restrict__ out) {
    __shared__ float fs[16][NC];
    __shared__ float fm[16][NC];

    const int b = blockIdx.x;
    const int t = threadIdx.x;
    const int c = t & 63;
    const int q = t >> 6;      // 0..15

    float s = 0.0f, m = -INFINITY;
    for (int blk = q; blk < BPB; blk += 16) {
        const float* w = ws + (size_t)(b * BPB + blk) * (2 * NC);
        s += w[c];
        m = fmaxf(m, w[NC + c]);
    }
    fs[q][c] = s;
    fm[q][c] = m;
    __syncthreads();

    if (t < NC) {
        float ts = 0.0f, tm = -INFINITY;
        #pragma unroll
        for (int q2 = 0; q2 < 16; ++q2) {
            ts += fs[q2][t];
            tm = fmaxf(tm, fm[q2][t]);
        }
        float avg = ts * (1.0f / (float)NS);
        float o   = fmaxf(avg + tm, 0.0f);
        float att = 1.0f / (1.0f + expf(-o * o));
        out[b * NC + t] = att;
    }
}

extern "C" void kernel_launch(void* const* d_in, const int* in_sizes, int n_in,
                              void* d_out, int out_size, void* d_ws, size_t ws_size,
                              hipStream_t stream) {
    const float* x = (const float*)d_in[0];
    float* ws  = (float*)d_ws;
    float* out = (float*)d_out;

    dim3 grid1(BPB, NB);
    ca_partial<<<grid1, 256, 0, stream>>>(x, ws);
    ca_final<<<NB, 1024, 0, stream>>>(ws, out);
}

// Round 5
// 226.497 us; speedup vs baseline: 2.3996x; 2.3996x over previous
//
#include <hip/hip_runtime.h>
#include <math.h>

// x fp32 [B=8, C=64, S=32*128*128=524288]
// norm over C, avg+max over S, relu, sigmoid(out^2) -> [B,C]
#define NC    64
#define NS    524288
#define NB    8
#define NW    16               // waves per block (1024 threads)
#define P     256              // positions per chunk (64 lanes x float4)
#define CHUNK 8                // chunks per block
#define BPB   256              // blocks per batch = NS/(CHUNK*P)

// Round-2 algorithm re-partitioned for occupancy: wave w owns channels
// 4w..4w+3 (4 float4 held = 16 VGPR, vs 16 float4 = 64), lane k owns
// positions 4k..4k+3. Per chunk: load, per-position nsq partial, one
// parity-double-buffered LDS exchange + one __syncthreads, normalize from
// registers. ~60 VGPR target -> 24-32 waves/CU (vs 12 in round 2).
__global__ __launch_bounds__(1024)
void ca_partial(const float* __restrict__ x, float* __restrict__ ws) {
    __shared__ float nsq_s[2][NW][P];   // 32 KB

    const int b   = blockIdx.y;
    const int blk = blockIdx.x;
    const int t   = threadIdx.x;
    const int w   = t >> 6;     // wave id 0..15
    const int k   = t & 63;     // lane

    float run_sum[4], run_max[4];
    #pragma unroll
    for (int i = 0; i < 4; ++i) { run_sum[i] = 0.0f; run_max[i] = -INFINITY; }

    // 4 channel-stream pointers (channels 4w+i), advanced by P each chunk
    const float* p0 = x + (size_t)b * NC * NS + (size_t)(4 * w + 0) * NS
                        + (size_t)blk * CHUNK * P + 4 * k;
    const float* p1 = p0 + (size_t)NS;
    const float* p2 = p0 + (size_t)2 * NS;
    const float* p3 = p0 + (size_t)3 * NS;

    for (int ch = 0; ch < CHUNK; ++ch) {
        // ---- load 4 channels x float4 (coalesced 16B/lane) ----
        const float4 v0 = *reinterpret_cast<const float4*>(p0);
        const float4 v1 = *reinterpret_cast<const float4*>(p1);
        const float4 v2 = *reinterpret_cast<const float4*>(p2);
        const float4 v3 = *reinterpret_cast<const float4*>(p3);
        p0 += P; p1 += P; p2 += P; p3 += P;

        // ---- per-position norm^2 partial over this wave's 4 channels ----
        float nx = v0.x * v0.x, ny = v0.y * v0.y, nz = v0.z * v0.z, nw2 = v0.w * v0.w;
        nx = fmaf(v1.x, v1.x, nx); ny = fmaf(v1.y, v1.y, ny);
        nz = fmaf(v1.z, v1.z, nz); nw2 = fmaf(v1.w, v1.w, nw2);
        nx = fmaf(v2.x, v2.x, nx); ny = fmaf(v2.y, v2.y, ny);
        nz = fmaf(v2.z, v2.z, nz); nw2 = fmaf(v2.w, v2.w, nw2);
        nx = fmaf(v3.x, v3.x, nx); ny = fmaf(v3.y, v3.y, ny);
        nz = fmaf(v3.z, v3.z, nz); nw2 = fmaf(v3.w, v3.w, nw2);

        // ---- cross-wave exchange (parity buffer, one barrier per chunk) ----
        const int par = ch & 1;
        *reinterpret_cast<float4*>(&nsq_s[par][w][4 * k]) = make_float4(nx, ny, nz, nw2);
        __syncthreads();

        float tx = 0.f, ty = 0.f, tz = 0.f, tw = 0.f;
        #pragma unroll
        for (int ww = 0; ww < NW; ++ww) {
            const float4 q = *reinterpret_cast<const float4*>(&nsq_s[par][ww][4 * k]);
            tx += q.x; ty += q.y; tz += q.z; tw += q.w;
        }
        const float rx = 1.0f / fmaxf(sqrtf(tx), 1e-12f);
        const float ry = 1.0f / fmaxf(sqrtf(ty), 1e-12f);
        const float rz = 1.0f / fmaxf(sqrtf(tz), 1e-12f);
        const float rw = 1.0f / fmaxf(sqrtf(tw), 1e-12f);

        // ---- normalize held registers, accumulate per-channel sum/max ----
        run_sum[0] = fmaf(v0.x, rx, run_sum[0]); run_sum[0] = fmaf(v0.y, ry, run_sum[0]);
        run_sum[0] = fmaf(v0.z, rz, run_sum[0]); run_sum[0] = fmaf(v0.w, rw, run_sum[0]);
        run_sum[1] = fmaf(v1.x, rx, run_sum[1]); run_sum[1] = fmaf(v1.y, ry, run_sum[1]);
        run_sum[1] = fmaf(v1.z, rz, run_sum[1]); run_sum[1] = fmaf(v1.w, rw, run_sum[1]);
        run_sum[2] = fmaf(v2.x, rx, run_sum[2]); run_sum[2] = fmaf(v2.y, ry, run_sum[2]);
        run_sum[2] = fmaf(v2.z, rz, run_sum[2]); run_sum[2] = fmaf(v2.w, rw, run_sum[2]);
        run_sum[3] = fmaf(v3.x, rx, run_sum[3]); run_sum[3] = fmaf(v3.y, ry, run_sum[3]);
        run_sum[3] = fmaf(v3.z, rz, run_sum[3]); run_sum[3] = fmaf(v3.w, rw, run_sum[3]);

        run_max[0] = fmaxf(run_max[0], fmaxf(fmaxf(v0.x * rx, v0.y * ry),
                                             fmaxf(v0.z * rz, v0.w * rw)));
        run_max[1] = fmaxf(run_max[1], fmaxf(fmaxf(v1.x * rx, v1.y * ry),
                                             fmaxf(v1.z * rz, v1.w * rw)));
        run_max[2] = fmaxf(run_max[2], fmaxf(fmaxf(v2.x * rx, v2.y * ry),
                                             fmaxf(v2.z * rz, v2.w * rw)));
        run_max[3] = fmaxf(run_max[3], fmaxf(fmaxf(v3.x * rx, v3.y * ry),
                                             fmaxf(v3.z * rz, v3.w * rw)));
    }

    // ---- one-time wave butterfly reduce, lane 0 writes partials ----
    float* wp = ws + (size_t)(b * BPB + blk) * (2 * NC);
    #pragma unroll
    for (int i = 0; i < 4; ++i) {
        float s = run_sum[i];
        float m = run_max[i];
        #pragma unroll
        for (int d = 32; d > 0; d >>= 1) {
            s += __shfl_xor(s, d, 64);
            m = fmaxf(m, __shfl_xor(m, d, 64));
        }
        if (k == 0) {
            wp[4 * w + i]      = s;   // channel c = 4w+i
            wp[NC + 4 * w + i] = m;
        }
    }
}

// Reduce BPB partials per (b,c), apply relu + sigmoid(out^2).
__global__ __launch_bounds__(1024)
void ca_final(const float* __restrict__ ws, float* __restrict__ out) {
    __shared__ float fs[16][NC];
    __shared__ float fm[16][NC];

    const int b = blockIdx.x;
    const int t = threadIdx.x;
    const int c = t & 63;
    const int q = t >> 6;      // 0..15

    float s = 0.0f, m = -INFINITY;
    for (int blk = q; blk < BPB; blk += 16) {
        const float* w = ws + (size_t)(b * BPB + blk) * (2 * NC);
        s += w[c];
        m = fmaxf(m, w[NC + c]);
    }
    fs[q][c] = s;
    fm[q][c] = m;
    __syncthreads();

    if (t < NC) {
        float ts = 0.0f, tm = -INFINITY;
        #pragma unroll
        for (int q2 = 0; q2 < 16; ++q2) {
            ts += fs[q2][t];
            tm = fmaxf(tm, fm[q2][t]);
        }
        float avg = ts * (1.0f / (float)NS);
        float o   = fmaxf(avg + tm, 0.0f);
        float att = 1.0f / (1.0f + expf(-o * o));
        out[b * NC + t] = att;
    }
}

extern "C" void kernel_launch(void* const* d_in, const int* in_sizes, int n_in,
                              void* d_out, int out_size, void* d_ws, size_t ws_size,
                              hipStream_t stream) {
    const float* x = (const float*)d_in[0];
    float* ws  = (float*)d_ws;
    float* out = (float*)d_out;

    dim3 grid1(BPB, NB);
    ca_partial<<<grid1, 1024, 0, stream>>>(x, ws);
    ca_final<<<NB, 1024, 0, stream>>>(ws, out);
}